// Round 1
// baseline (857.930 us; speedup 1.0000x reference)
//
#include <hip/hip_runtime.h>
#include <math.h>

#define CCH   512
#define HW    64
#define FXY   7
#define BINS  49                 // 7*7
#define POOL_LEN (CCH * BINS)    // 25088
#define NPOOLS 16
#define D_IN  (POOL_LEN * 6)     // 150528
#define NOUT  1024
#define KPB   147                // 150528 / 1024
#define NKB   1024

// ---------------------------------------------------------------------------
// Region bounds for pool p:
//   p = 0        : scene (full 64x64)
//   p = 1..3     : human i = p-1
//   p = 4..15    : union(person i, obj j), i = (p-4)/4, j = (p-4)%4
// jnp.round == round-half-to-even == rintf (default rounding mode).
// ---------------------------------------------------------------------------
__device__ __forceinline__ void region_of(int p, const float* pb, const float* ob,
                                          float r0, float r1,
                                          int& x0, int& y0, int& x1, int& y1) {
    if (p == 0) { x0 = 0; y0 = 0; x1 = HW; y1 = HW; return; }
    if (p <= 3) {
        int i = p - 1;
        x0 = (int)rintf(pb[i * 4 + 0] * r0);
        y0 = (int)rintf(pb[i * 4 + 1] * r1);
        x1 = (int)rintf(pb[i * 4 + 2] * r0);
        y1 = (int)rintf(pb[i * 4 + 3] * r1);
        return;
    }
    int i = (p - 4) >> 2, j = (p - 4) & 3;
    int px0 = (int)rintf(pb[i * 4 + 0] * r0), py0 = (int)rintf(pb[i * 4 + 1] * r1);
    int px1 = (int)rintf(pb[i * 4 + 2] * r0), py1 = (int)rintf(pb[i * 4 + 3] * r1);
    int ox0 = (int)rintf(ob[j * 4 + 0] * r0), oy0 = (int)rintf(ob[j * 4 + 1] * r1);
    int ox1 = (int)rintf(ob[j * 4 + 2] * r0), oy1 = (int)rintf(ob[j * 4 + 3] * r1);
    x0 = min(px0, ox0); y0 = min(py0, oy0);
    x1 = max(px1, ox1); y1 = max(py1, oy1);
}

// out[m*1024+n] = bias[n]
__global__ void init_out(const float* __restrict__ b, float* __restrict__ out) {
    int o = blockIdx.x * blockDim.x + threadIdx.x;
    if (o < 3 * NOUT) out[o] = b[o & (NOUT - 1)];
}

// One wave per (pool, channel). grid = (16, 128), block = 256 (4 waves).
// Phase 1: lane = x-column; per row-bin i compute column max (coalesced
//          64-lane row loads). Phase 2: 49 lanes reduce columns -> bins.
// Output layout: pools[p][c*49 + i*7 + j]   (channel-major, matches
// transpose(pooled,(1,0,2)).reshape(-1)).
__global__ __launch_bounds__(256) void pool_kernel(
        const float* __restrict__ feat, const float* __restrict__ pb,
        const float* __restrict__ ob, const float* __restrict__ ratio,
        float* __restrict__ pools) {
    int p    = blockIdx.x;
    int wv   = threadIdx.x >> 6;
    int lane = threadIdx.x & 63;
    int c    = blockIdx.y * 4 + wv;

    int x0, y0, x1, y1;
    region_of(p, pb, ob, ratio[0], ratio[1], x0, y0, x1, y1);
    int h = y1 - y0, w = x1 - x0;

    __shared__ float cm[4][FXY][HW];   // [wave][row-bin][x-rel] column maxes

    const float* f = feat + (size_t)c * (HW * HW);
    #pragma unroll
    for (int i = 0; i < FXY; ++i) {
        int rs = y0 + (i * h) / FXY;
        int re = y0 + ((i + 1) * h + FXY - 1) / FXY;   // ceil
        float m = -INFINITY;
        if (lane < w) {
            const float* fp = f + rs * HW + x0 + lane;
            for (int y = rs; y < re; ++y, fp += HW) m = fmaxf(m, *fp);
        }
        cm[wv][i][lane] = m;
    }
    __syncthreads();

    if (lane < BINS) {
        int i = lane / FXY, j = lane % FXY;
        int cs = (j * w) / FXY;
        int ce = ((j + 1) * w + FXY - 1) / FXY;        // ceil, relative to x0
        float m = -INFINITY;
        for (int x = cs; x < ce; ++x) m = fmaxf(m, cm[wv][i][x]);
        pools[(size_t)p * POOL_LEN + c * BINS + lane] = m;
    }
}

// K-split GEMV: out[3,1024] += total[3, k0:k0+147] @ W[k0:k0+147, 1024].
// total[m][k] gathered from pools by segment:
//   s = k/25088: s==0 -> human[m] (pool 1+m); s in 1..4 -> union(m, s-1)
//   (pool 4 + m*4 + s-1); s==5 -> scene (pool 0, shared by all m).
__global__ __launch_bounds__(256) void gemv_kernel(
        const float* __restrict__ pools, const float* __restrict__ W,
        float* __restrict__ out) {
    int k0 = blockIdx.x * KPB;
    __shared__ float t[3][KPB];
    for (int kk = threadIdx.x; kk < KPB; kk += 256) {
        int k = k0 + kk;
        int s = k / POOL_LEN, rr = k - s * POOL_LEN;
        #pragma unroll
        for (int m = 0; m < 3; ++m) {
            int pi = (s == 0) ? (1 + m) : ((s == 5) ? 0 : (4 + m * 4 + (s - 1)));
            t[m][kk] = pools[(size_t)pi * POOL_LEN + rr];
        }
    }
    __syncthreads();

    int n0 = threadIdx.x * 4;
    float acc[3][4] = {};
    const float4* Wp = (const float4*)(W + (size_t)k0 * NOUT + n0);
    #pragma unroll 7
    for (int kk = 0; kk < KPB; ++kk) {
        float4 w4 = Wp[(size_t)kk * (NOUT / 4)];
        float t0 = t[0][kk], t1 = t[1][kk], t2 = t[2][kk];
        acc[0][0] += t0 * w4.x; acc[0][1] += t0 * w4.y;
        acc[0][2] += t0 * w4.z; acc[0][3] += t0 * w4.w;
        acc[1][0] += t1 * w4.x; acc[1][1] += t1 * w4.y;
        acc[1][2] += t1 * w4.z; acc[1][3] += t1 * w4.w;
        acc[2][0] += t2 * w4.x; acc[2][1] += t2 * w4.y;
        acc[2][2] += t2 * w4.z; acc[2][3] += t2 * w4.w;
    }
    #pragma unroll
    for (int m = 0; m < 3; ++m) {
        atomicAdd(&out[m * NOUT + n0 + 0], acc[m][0]);
        atomicAdd(&out[m * NOUT + n0 + 1], acc[m][1]);
        atomicAdd(&out[m * NOUT + n0 + 2], acc[m][2]);
        atomicAdd(&out[m * NOUT + n0 + 3], acc[m][3]);
    }
}

extern "C" void kernel_launch(void* const* d_in, const int* in_sizes, int n_in,
                              void* d_out, int out_size, void* d_ws, size_t ws_size,
                              hipStream_t stream) {
    const float* feature = (const float*)d_in[0];   // [1,512,64,64]
    const float* pb      = (const float*)d_in[1];   // [3,4]
    const float* ob      = (const float*)d_in[2];   // [4,4]
    const float* ratio   = (const float*)d_in[3];   // [2]
    const float* W       = (const float*)d_in[4];   // [150528,1024]
    const float* bias    = (const float*)d_in[5];   // [1024]
    float* out   = (float*)d_out;                   // [3,1024]
    float* pools = (float*)d_ws;                    // 16 * 25088 floats = 1.6 MB

    hipLaunchKernelGGL(init_out, dim3(12), dim3(256), 0, stream, bias, out);
    hipLaunchKernelGGL(pool_kernel, dim3(NPOOLS, CCH / 4), dim3(256), 0, stream,
                       feature, pb, ob, ratio, pools);
    hipLaunchKernelGGL(gemv_kernel, dim3(NKB), dim3(256), 0, stream,
                       pools, W, out);
}

// Round 2
// 820.462 us; speedup vs baseline: 1.0457x; 1.0457x over previous
//
#include <hip/hip_runtime.h>
#include <math.h>

#define CCH   512
#define HW    64
#define FXY   7
#define BINS  49                 // 7*7
#define POOL_LEN (CCH * BINS)    // 25088
#define NPOOLS 16
#define D_IN  (POOL_LEN * 6)     // 150528
#define NOUT  1024
#define KPB   588                // rows of W per k-block
#define NKB   256                // 256 * 588 = 150528

// ---------------------------------------------------------------------------
// Region bounds for pool p:
//   p = 0        : scene (full 64x64)
//   p = 1..3     : human i = p-1
//   p = 4..15    : union(person i, obj j), i = (p-4)/4, j = (p-4)%4
// jnp.round == round-half-to-even == rintf (default rounding mode).
// ---------------------------------------------------------------------------
__device__ __forceinline__ void region_of(int p, const float* pb, const float* ob,
                                          float r0, float r1,
                                          int& x0, int& y0, int& x1, int& y1) {
    if (p == 0) { x0 = 0; y0 = 0; x1 = HW; y1 = HW; return; }
    if (p <= 3) {
        int i = p - 1;
        x0 = (int)rintf(pb[i * 4 + 0] * r0);
        y0 = (int)rintf(pb[i * 4 + 1] * r1);
        x1 = (int)rintf(pb[i * 4 + 2] * r0);
        y1 = (int)rintf(pb[i * 4 + 3] * r1);
        return;
    }
    int i = (p - 4) >> 2, j = (p - 4) & 3;
    int px0 = (int)rintf(pb[i * 4 + 0] * r0), py0 = (int)rintf(pb[i * 4 + 1] * r1);
    int px1 = (int)rintf(pb[i * 4 + 2] * r0), py1 = (int)rintf(pb[i * 4 + 3] * r1);
    int ox0 = (int)rintf(ob[j * 4 + 0] * r0), oy0 = (int)rintf(ob[j * 4 + 1] * r1);
    int ox1 = (int)rintf(ob[j * 4 + 2] * r0), oy1 = (int)rintf(ob[j * 4 + 3] * r1);
    x0 = min(px0, ox0); y0 = min(py0, oy0);
    x1 = max(px1, ox1); y1 = max(py1, oy1);
}

// One wave per (pool, channel). grid = (16, 128), block = 256 (4 waves).
__global__ __launch_bounds__(256) void pool_kernel(
        const float* __restrict__ feat, const float* __restrict__ pb,
        const float* __restrict__ ob, const float* __restrict__ ratio,
        float* __restrict__ pools) {
    int p    = blockIdx.x;
    int wv   = threadIdx.x >> 6;
    int lane = threadIdx.x & 63;
    int c    = blockIdx.y * 4 + wv;

    int x0, y0, x1, y1;
    region_of(p, pb, ob, ratio[0], ratio[1], x0, y0, x1, y1);
    int h = y1 - y0, w = x1 - x0;

    __shared__ float cm[4][FXY][HW];   // [wave][row-bin][x-rel] column maxes

    const float* f = feat + (size_t)c * (HW * HW);
    #pragma unroll
    for (int i = 0; i < FXY; ++i) {
        int rs = y0 + (i * h) / FXY;
        int re = y0 + ((i + 1) * h + FXY - 1) / FXY;   // ceil
        float m = -INFINITY;
        if (lane < w) {
            const float* fp = f + rs * HW + x0 + lane;
            for (int y = rs; y < re; ++y, fp += HW) m = fmaxf(m, *fp);
        }
        cm[wv][i][lane] = m;
    }
    __syncthreads();

    if (lane < BINS) {
        int i = lane / FXY, j = lane % FXY;
        int cs = (j * w) / FXY;
        int ce = ((j + 1) * w + FXY - 1) / FXY;        // ceil, relative to x0
        float m = -INFINITY;
        for (int x = cs; x < ce; ++x) m = fmaxf(m, cm[wv][i][x]);
        pools[(size_t)p * POOL_LEN + c * BINS + lane] = m;
    }
}

// K-split GEMV, atomic-free: block b computes partial[b][3][1024] over rows
// [b*588, (b+1)*588) of W. 256 blocks (1/CU, 4 waves) stream W with float4.
// total[m][k] gathered from pools by segment:
//   s = k/25088: s==0 -> human[m] (pool 1+m); s in 1..4 -> union(m, s-1)
//   (pool 4 + m*4 + s-1); s==5 -> scene (pool 0, shared by all m).
__global__ __launch_bounds__(256) void gemv_kernel(
        const float* __restrict__ pools, const float* __restrict__ W,
        float* __restrict__ pf) {
    int b  = blockIdx.x;
    int k0 = b * KPB;
    __shared__ float t[3][KPB];
    for (int kk = threadIdx.x; kk < KPB; kk += 256) {
        int k = k0 + kk;
        int s = k / POOL_LEN, rr = k - s * POOL_LEN;
        #pragma unroll
        for (int m = 0; m < 3; ++m) {
            int pi = (s == 0) ? (1 + m) : ((s == 5) ? 0 : (4 + m * 4 + (s - 1)));
            t[m][kk] = pools[(size_t)pi * POOL_LEN + rr];
        }
    }
    __syncthreads();

    int n0 = threadIdx.x * 4;
    float acc[3][4] = {};
    const float4* Wp = (const float4*)(W + (size_t)k0 * NOUT + n0);
    #pragma unroll 8
    for (int kk = 0; kk < KPB; ++kk) {
        float4 w4 = Wp[(size_t)kk * (NOUT / 4)];
        float t0 = t[0][kk], t1 = t[1][kk], t2 = t[2][kk];
        acc[0][0] += t0 * w4.x; acc[0][1] += t0 * w4.y;
        acc[0][2] += t0 * w4.z; acc[0][3] += t0 * w4.w;
        acc[1][0] += t1 * w4.x; acc[1][1] += t1 * w4.y;
        acc[1][2] += t1 * w4.z; acc[1][3] += t1 * w4.w;
        acc[2][0] += t2 * w4.x; acc[2][1] += t2 * w4.y;
        acc[2][2] += t2 * w4.z; acc[2][3] += t2 * w4.w;
    }
    // coalesced partial store: pf[b][m][n0..n0+3]
    #pragma unroll
    for (int m = 0; m < 3; ++m) {
        ((float4*)(pf + (size_t)b * (3 * NOUT) + m * NOUT))[threadIdx.x] =
            make_float4(acc[m][0], acc[m][1], acc[m][2], acc[m][3]);
    }
}

// Sum 256 partials per output, add bias. 48 blocks x 256 threads; block
// handles 64 consecutive outputs, 4 wave-groups split the b-range.
__global__ __launch_bounds__(256) void reduce_kernel(
        const float* __restrict__ pf, const float* __restrict__ bias,
        float* __restrict__ out) {
    int o0 = blockIdx.x * 64;          // 48 blocks cover 3072 outputs
    int lo = threadIdx.x & 63;
    int g  = threadIdx.x >> 6;         // 0..3: b-range quarter
    const float* p = pf + (size_t)(g * 64) * (3 * NOUT) + o0 + lo;
    float s0 = 0, s1 = 0, s2 = 0, s3 = 0;
    #pragma unroll 4
    for (int i = 0; i < 64; i += 4) {
        s0 += p[(size_t)(i + 0) * (3 * NOUT)];
        s1 += p[(size_t)(i + 1) * (3 * NOUT)];
        s2 += p[(size_t)(i + 2) * (3 * NOUT)];
        s3 += p[(size_t)(i + 3) * (3 * NOUT)];
    }
    float s = (s0 + s1) + (s2 + s3);
    __shared__ float sm[4][64];
    sm[g][lo] = s;
    __syncthreads();
    if (g == 0) {
        int o = o0 + lo;
        float tot = (sm[0][lo] + sm[1][lo]) + (sm[2][lo] + sm[3][lo]);
        out[o] = bias[o & (NOUT - 1)] + tot;
    }
}

extern "C" void kernel_launch(void* const* d_in, const int* in_sizes, int n_in,
                              void* d_out, int out_size, void* d_ws, size_t ws_size,
                              hipStream_t stream) {
    const float* feature = (const float*)d_in[0];   // [1,512,64,64]
    const float* pb      = (const float*)d_in[1];   // [3,4]
    const float* ob      = (const float*)d_in[2];   // [4,4]
    const float* ratio   = (const float*)d_in[3];   // [2]
    const float* W       = (const float*)d_in[4];   // [150528,1024]
    const float* bias    = (const float*)d_in[5];   // [1024]
    float* out   = (float*)d_out;                   // [3,1024]
    float* pools = (float*)d_ws;                    // 16*25088 floats = 1.6 MB
    float* pf    = pools + (size_t)NPOOLS * POOL_LEN;  // 256*3072 floats = 3 MB

    hipLaunchKernelGGL(pool_kernel, dim3(NPOOLS, CCH / 4), dim3(256), 0, stream,
                       feature, pb, ob, ratio, pools);
    hipLaunchKernelGGL(gemv_kernel, dim3(NKB), dim3(256), 0, stream,
                       pools, W, pf);
    hipLaunchKernelGGL(reduce_kernel, dim3(3 * NOUT / 64), dim3(256), 0, stream,
                       pf, bias, out);
}